// Round 4
// baseline (353.486 us; speedup 1.0000x reference)
//
#include <hip/hip_runtime.h>

constexpr int B_ = 64;
constexpr int T_ = 2048;
constexpr int H_ = 256;
constexpr float NEGINF = -1e10f;  // matches reference -10**10

// ---------------------------------------------------------------------------
// Fully fused: energy + masked fill + (last-block-per-row) softmax.
//
// Grid: dim3(T/256, B) = (8, 64), 256 threads/block. Block (x=cb, y=bb) owns
// tokens [cb*256, cb*256+256) of batch row bb.
//
// Math: e[b,t] = q[b,t] . u  with u = W^T v.  The bias term v.b is a uniform
// shift of all VALID entries of a row; masked entries are exactly -1e10 in
// both formulations, so softmax output is identical (verified: absmax 0.0).
//
// u is computed cooperatively per block into LDS (thread h does a 256-FMA
// column dot; W rows are coalesced and L2-resident across blocks — only one
// HBM fetch of W per XCD). This removes the separate prep kernel + launch
// dependency. Fully-masked blocks skip both W and q traffic entirely.
//
// q loop: thread = (tg = tid>>3 token group, c4 = tid&7 float4 column chunk).
// 8 tokens/thread x 8 float4 loads each, 128 B contiguous per 8-lane group.
// Fast path (whole chunk valid) has NO per-i branches -> maximal load
// batching. Reduce = 3-step shfl_xor over 8 lanes, 8 independent chains.
//
// Softmax: after writing its e chunk, each block does threadfence + atomicAdd
// on its row counter (device scope, cross-XCD safe). The 8th (last) block of
// the row acquires (fence) and runs the row softmax — overlapping softmax of
// early-finished rows with energy streaming of the rest. Masked entries
// (-1e10) underflow to exp()=0 exactly as the reference.
// ---------------------------------------------------------------------------
__global__ __launch_bounds__(256) void fused_kernel(
    const float4* __restrict__ q4, const int* __restrict__ lens,
    const float* __restrict__ W, const float* __restrict__ v,
    float* __restrict__ e, unsigned int* __restrict__ row_cnt,
    float* __restrict__ out) {
  const int bb = blockIdx.y;
  const int t0 = blockIdx.x * 256;
  const int tid = threadIdx.x;
  const int len = lens[bb];
  float* erow = e + (size_t)bb * T_;

  __shared__ float su[H_];
  __shared__ int s_last;

  if (t0 < len) {
    // ---- cooperative u = W^T v into LDS ----
    float uacc = 0.f;
#pragma unroll 8
    for (int k = 0; k < H_; ++k) uacc = fmaf(v[k], W[k * H_ + tid], uacc);
    su[tid] = uacc;
    __syncthreads();

    const int tg = tid >> 3;  // 0..31
    const int c4 = tid & 7;   // 0..7
    float4 uf[8];
#pragma unroll
    for (int hh = 0; hh < 8; ++hh)
      uf[hh] = reinterpret_cast<const float4*>(su)[hh * 8 + c4];

    const float4* qbase =
        q4 + ((size_t)bb * T_ + t0 + tg) * (H_ / 4) + c4;

    float acc[8];
#pragma unroll
    for (int i = 0; i < 8; ++i) acc[i] = 0.f;

    if (t0 + 256 <= len) {
      // ---- fast path: whole chunk valid, branch-free ----
#pragma unroll
      for (int i = 0; i < 8; ++i) {
        const float4* qp = qbase + (size_t)i * 32 * (H_ / 4);
#pragma unroll
        for (int hh = 0; hh < 8; ++hh) {
          const float4 qv = qp[hh * 8];
          acc[i] = fmaf(qv.x, uf[hh].x, acc[i]);
          acc[i] = fmaf(qv.y, uf[hh].y, acc[i]);
          acc[i] = fmaf(qv.z, uf[hh].z, acc[i]);
          acc[i] = fmaf(qv.w, uf[hh].w, acc[i]);
        }
      }
    } else {
      // ---- boundary chunk: per-token-group predication ----
#pragma unroll
      for (int i = 0; i < 8; ++i) {
        const int t = t0 + tg + 32 * i;
        if (t < len) {
          const float4* qp = qbase + (size_t)i * 32 * (H_ / 4);
#pragma unroll
          for (int hh = 0; hh < 8; ++hh) {
            const float4 qv = qp[hh * 8];
            acc[i] = fmaf(qv.x, uf[hh].x, acc[i]);
            acc[i] = fmaf(qv.y, uf[hh].y, acc[i]);
            acc[i] = fmaf(qv.z, uf[hh].z, acc[i]);
            acc[i] = fmaf(qv.w, uf[hh].w, acc[i]);
          }
        }
      }
    }

    // sum across the 8 column-chunk lanes (3-step butterfly, 8 ILP chains)
#pragma unroll
    for (int off = 1; off < 8; off <<= 1) {
#pragma unroll
      for (int i = 0; i < 8; ++i) acc[i] += __shfl_xor(acc[i], off);
    }

    float val = 0.f;
#pragma unroll
    for (int k = 0; k < 8; ++k)
      if (c4 == k) val = acc[k];
    const int t = t0 + tg + 32 * c4;
    erow[t] = (t < len) ? val : NEGINF;
  } else {
    // fully masked chunk: no W / q traffic at all
    erow[t0 + tid] = NEGINF;
  }

  // ---- last-block-of-row election ----
  __threadfence();  // release: e chunk visible device-wide
  if (tid == 0) {
    const unsigned int old = atomicAdd(&row_cnt[bb], 1u);
    s_last = (old == gridDim.x - 1) ? 1 : 0;
  }
  __syncthreads();
  if (!s_last) return;
  __threadfence();  // acquire: other blocks' e chunks visible

  // ---- row softmax (2048 values, 8 regs/thread) ----
  const int wave = tid >> 6;
  const int lane = tid & 63;
  float* orow = out + (size_t)bb * T_;

  float vals[T_ / 256];
  float m = NEGINF;
#pragma unroll
  for (int i = 0; i < T_ / 256; ++i) {
    vals[i] = erow[i * 256 + tid];
    m = fmaxf(m, vals[i]);
  }
#pragma unroll
  for (int off = 32; off > 0; off >>= 1) m = fmaxf(m, __shfl_xor(m, off));

  __shared__ float sm[4];
  __shared__ float ssum[4];
  if (lane == 0) sm[wave] = m;
  __syncthreads();
  m = fmaxf(fmaxf(sm[0], sm[1]), fmaxf(sm[2], sm[3]));

  float s = 0.f;
#pragma unroll
  for (int i = 0; i < T_ / 256; ++i) {
    vals[i] = expf(vals[i] - m);
    s += vals[i];
  }
#pragma unroll
  for (int off = 32; off > 0; off >>= 1) s += __shfl_xor(s, off);
  if (lane == 0) ssum[wave] = s;
  __syncthreads();
  s = ssum[0] + ssum[1] + ssum[2] + ssum[3];
  const float inv = 1.f / s;
#pragma unroll
  for (int i = 0; i < T_ / 256; ++i) orow[i * 256 + tid] = vals[i] * inv;
}

// ---------------------------------------------------------------------------
extern "C" void kernel_launch(void* const* d_in, const int* in_sizes, int n_in,
                              void* d_out, int out_size, void* d_ws,
                              size_t ws_size, hipStream_t stream) {
  const float* q = (const float*)d_in[0];     // [B,T,H]
  const int* lens = (const int*)d_in[1];      // [B]
  const float* W = (const float*)d_in[2];     // [H,H]
  // d_in[3] = bias, d_in[4] = v; bias unused (softmax shift-invariance)
  const float* v = (const float*)d_in[4];
  float* out = (float*)d_out;                 // [B,T]

  char* ws = (char*)d_ws;
  float* e = (float*)ws;                             // B*T floats = 512 KiB
  unsigned int* row_cnt =
      (unsigned int*)(ws + (size_t)B_ * T_ * sizeof(float));  // 64 uints

  // ws is poisoned 0xAA before every call: zero the row counters (async,
  // graph-capture-safe — the harness itself uses hipMemsetAsync).
  hipMemsetAsync(row_cnt, 0, B_ * sizeof(unsigned int), stream);

  fused_kernel<<<dim3(T_ / 256, B_), dim3(256), 0, stream>>>(
      (const float4*)q, lens, W, v, e, row_cnt, (float*)d_out);
}

// Round 5
// 196.678 us; speedup vs baseline: 1.7973x; 1.7973x over previous
//
#include <hip/hip_runtime.h>

constexpr int B_ = 64;
constexpr int T_ = 2048;
constexpr int H_ = 256;
constexpr float NEGINF = -1e10f;  // matches reference -10**10

// ---------------------------------------------------------------------------
// prep: 4 blocks; block j computes partial[j][h] = sum_{k in [64j,64j+64)}
// v[k] * W[k][h].  (u[h] = sum_j partial[j][h] is folded into energy_kernel.)
// Bias term v.b dropped: uniform shift of valid entries; softmax-invariant
// (masked entries are exactly -1e10 either way). Verified absmax 0.0 in R2.
// ---------------------------------------------------------------------------
__global__ __launch_bounds__(256) void prep_kernel(
    const float* __restrict__ W, const float* __restrict__ v,
    float* __restrict__ partial) {
  const int h = threadIdx.x;
  const int j = blockIdx.x;  // 0..3
  float acc = 0.f;
#pragma unroll 8
  for (int kk = 0; kk < 64; ++kk) {
    const int k = j * 64 + kk;
    acc = fmaf(v[k], W[k * H_ + h], acc);
  }
  partial[j * H_ + h] = acc;
}

// ---------------------------------------------------------------------------
// energy: for t < len[b]:  e[b,t] = q[b,t] . u   (u = W^T v)
//         for t >= len[b]: out[b,t] = 0 directly; e not written.
// (Masked softmax outputs are EXACTLY 0: valid energies ~N(0,1) so the row
// max m is small, and expf(-1e10 - m) underflows to +0; 0/sum = 0.)
//
// Block = 256 threads <-> 256 tokens [t0, t0+256) of row bb.
//   tg = tid>>3 token group, c4 = tid&7 float4 column chunk.
//   uf preloaded from the 4 prep partials (L2-hot).
//   8 tokens/thread x 8 float4 loads (128B contiguous per 8-lane group),
//   fast path branch-free; 3-step shfl_xor butterfly over 8 lanes.
// NO device-scope fences/atomics anywhere (R4 lesson: ~180 us L2-maintenance
// stall). Kernel boundary provides the cross-XCD visibility for e.
// ---------------------------------------------------------------------------
__global__ __launch_bounds__(256) void energy_kernel(
    const float4* __restrict__ q4, const int* __restrict__ lens,
    const float4* __restrict__ p4,  // [4][64] float4 partials of u
    float* __restrict__ e, float* __restrict__ out) {
  const int bb = blockIdx.y;
  const int t0 = blockIdx.x * 256;
  const int len = lens[bb];
  const int tid = threadIdx.x;
  float* erow = e + (size_t)bb * T_;
  float* orow = out + (size_t)bb * T_;

  if (t0 >= len) {  // fully masked chunk: final output is exactly 0
    orow[t0 + tid] = 0.f;
    return;
  }

  const int tg = tid >> 3;  // 0..31
  const int c4 = tid & 7;   // 0..7

  float4 uf[8];
#pragma unroll
  for (int hh = 0; hh < 8; ++hh) {
    float4 s = p4[hh * 8 + c4];
#pragma unroll
    for (int j = 1; j < 4; ++j) {
      const float4 t = p4[j * 64 + hh * 8 + c4];
      s.x += t.x; s.y += t.y; s.z += t.z; s.w += t.w;
    }
    uf[hh] = s;
  }

  const float4* qbase =
      q4 + ((size_t)bb * T_ + t0 + tg) * (H_ / 4) + c4;

  float acc[8];
#pragma unroll
  for (int i = 0; i < 8; ++i) acc[i] = 0.f;

  if (t0 + 256 <= len) {
    // fast path: whole chunk valid, branch-free -> maximal load batching
#pragma unroll
    for (int i = 0; i < 8; ++i) {
      const float4* qp = qbase + (size_t)i * 32 * (H_ / 4);
#pragma unroll
      for (int hh = 0; hh < 8; ++hh) {
        const float4 qv = qp[hh * 8];
        acc[i] = fmaf(qv.x, uf[hh].x, acc[i]);
        acc[i] = fmaf(qv.y, uf[hh].y, acc[i]);
        acc[i] = fmaf(qv.z, uf[hh].z, acc[i]);
        acc[i] = fmaf(qv.w, uf[hh].w, acc[i]);
      }
    }
  } else {
    // boundary chunk: per-token-group predication
#pragma unroll
    for (int i = 0; i < 8; ++i) {
      const int t = t0 + tg + 32 * i;
      if (t < len) {
        const float4* qp = qbase + (size_t)i * 32 * (H_ / 4);
#pragma unroll
        for (int hh = 0; hh < 8; ++hh) {
          const float4 qv = qp[hh * 8];
          acc[i] = fmaf(qv.x, uf[hh].x, acc[i]);
          acc[i] = fmaf(qv.y, uf[hh].y, acc[i]);
          acc[i] = fmaf(qv.z, uf[hh].z, acc[i]);
          acc[i] = fmaf(qv.w, uf[hh].w, acc[i]);
        }
      }
    }
  }

  // sum across the 8 column-chunk lanes (3-step butterfly, 8 ILP chains)
#pragma unroll
  for (int off = 1; off < 8; off <<= 1) {
#pragma unroll
    for (int i = 0; i < 8; ++i) acc[i] += __shfl_xor(acc[i], off);
  }

  float val = 0.f;
#pragma unroll
  for (int k = 0; k < 8; ++k)
    if (c4 == k) val = acc[k];
  const int t = t0 + tg + 32 * c4;
  if (t < len) erow[t] = val;
  else         orow[t] = 0.f;  // boundary chunk's masked tail
}

// ---------------------------------------------------------------------------
// softmax over the VALID prefix only. One block per row; masked outputs were
// already written as 0 by energy_kernel, and e[t>=len] is never read (it was
// never written — ws holds poison there).
// ---------------------------------------------------------------------------
__global__ __launch_bounds__(256) void softmax_kernel(
    const float* __restrict__ e, const int* __restrict__ lens,
    float* __restrict__ out) {
  const int bb = blockIdx.x;
  const int tid = threadIdx.x;
  const int wave = tid >> 6;
  const int lane = tid & 63;
  const int len = lens[bb];
  const float* erow = e + (size_t)bb * T_;
  float* orow = out + (size_t)bb * T_;

  float vals[T_ / 256];  // 8
  float m = NEGINF;
#pragma unroll
  for (int i = 0; i < T_ / 256; ++i) {
    if (i * 256 < len) {  // uniform chunk-level skip
      const int t = i * 256 + tid;
      vals[i] = (t < len) ? erow[t] : NEGINF;  // lane-predicated load
      m = fmaxf(m, vals[i]);
    } else {
      vals[i] = NEGINF;
    }
  }
#pragma unroll
  for (int off = 32; off > 0; off >>= 1) m = fmaxf(m, __shfl_xor(m, off));

  __shared__ float sm[4];
  __shared__ float ssum[4];
  if (lane == 0) sm[wave] = m;
  __syncthreads();
  m = fmaxf(fmaxf(sm[0], sm[1]), fmaxf(sm[2], sm[3]));

  float s = 0.f;
#pragma unroll
  for (int i = 0; i < T_ / 256; ++i) {
    if (i * 256 < len) {
      vals[i] = expf(vals[i] - m);  // NEGINF lanes underflow to exactly 0
      s += vals[i];
    }
  }
#pragma unroll
  for (int off = 32; off > 0; off >>= 1) s += __shfl_xor(s, off);
  if (lane == 0) ssum[wave] = s;
  __syncthreads();
  s = ssum[0] + ssum[1] + ssum[2] + ssum[3];
  const float inv = 1.f / s;
#pragma unroll
  for (int i = 0; i < T_ / 256; ++i) {
    if (i * 256 < len) {
      const int t = i * 256 + tid;
      if (t < len) orow[t] = vals[i] * inv;  // masked tail already 0
    }
  }
}

// ---------------------------------------------------------------------------
extern "C" void kernel_launch(void* const* d_in, const int* in_sizes, int n_in,
                              void* d_out, int out_size, void* d_ws,
                              size_t ws_size, hipStream_t stream) {
  const float* q = (const float*)d_in[0];     // [B,T,H]
  const int* lens = (const int*)d_in[1];      // [B]
  const float* W = (const float*)d_in[2];     // [H,H]
  // d_in[3] = bias, d_in[4] = v; bias unused (softmax shift-invariance)
  const float* v = (const float*)d_in[4];
  float* out = (float*)d_out;                 // [B,T]

  char* ws = (char*)d_ws;
  float* partial = (float*)ws;                  // 4*256 floats = 4 KiB
  float* e = (float*)(ws + 8192);               // B*T floats = 512 KiB

  prep_kernel<<<dim3(4), dim3(256), 0, stream>>>(W, v, partial);
  energy_kernel<<<dim3(T_ / 256, B_), dim3(256), 0, stream>>>(
      (const float4*)q, lens, (const float4*)partial, e, out);
  softmax_kernel<<<dim3(B_), dim3(256), 0, stream>>>(e, lens, out);
}